// Round 14
// baseline (2575.574 us; speedup 1.0000x reference)
//
#include <hip/hip_runtime.h>
#include <cmath>

#define HID 51
#define BATCH 256
#define BLK 832      // 13 waves: wave w owns slot rows 16w..16w+15

typedef _Float16 half8 __attribute__((ext_vector_type(8)));
typedef float    f32x4 __attribute__((ext_vector_type(4)));

// MFMA LSTM. Slot space s=0..207: unit u=s>>2, gate gt=s&3 -> torch row
// r=gt*51+u. Slot 204 (layer2 only) = output row (Wl over the h2 half);
// 205..207 = zero rows.
// Per tick tau, wave w computes D(16x16) = A(16x32) x B(32x16) chains:
//   l0 (t=tau):   k=[h0(51), x_hi, x_lo, 0...]          (2 k-tiles)
//   l1 (t=tau-1): k=[h0; h1; 0...]                      (4 k-tiles)
//   l2 (t=tau-2): k=[h1; h2; 0...]                      (4 k-tiles)
// B = v replicated across columns: lane's frag = v[quad*8+j] -> one broadcast
// ds_read_b128 per k-tile. A frag: A[m=lane&15][k=quad*8+j], rows = slots
// 16w+m (weights loaded once, kernel-lifetime registers). D layout:
// col=lane&15, row=quad*4+reg -> lane (quad,.) holds ALL 4 gates of unit
// u=4w+quad -> cell update fully in-wave/in-register; m==0 lanes write h
// (f16) into the OTHER v buffer (dbuf) -> ONE barrier per tick. Bias folded
// into acc init. Output: g2[0] of (wave12,lane48) = bl + Wl.h2(tau-3) ->
// obuf ring, flushed 64-wide by wave 1 every 64 ticks.

__device__ __forceinline__ float fsig(float v) {
    return __builtin_amdgcn_rcpf(1.f + __expf(-v));
}
__device__ __forceinline__ float ftanh(float v) {
    const float e = __expf(2.f * v);                  // inf-safe
    return fmaf(-2.f, __builtin_amdgcn_rcpf(e + 1.f), 1.f);
}

__attribute__((amdgpu_waves_per_eu(4, 4)))
__global__ __launch_bounds__(BLK)
void lstm3_kernel(const float* __restrict__ x,
                  const float* __restrict__ Wih1, const float* __restrict__ Whh1,
                  const float* __restrict__ bih1, const float* __restrict__ bhh1,
                  const float* __restrict__ Wih,  const float* __restrict__ Whh,
                  const float* __restrict__ bih,  const float* __restrict__ bhh,
                  const float* __restrict__ Wl,   const float* __restrict__ bl,
                  float* __restrict__ out, int T)
{
    const int b    = blockIdx.x;
    const int tid  = threadIdx.x;
    const int wave = tid >> 6;
    const int lane = tid & 63;
    const int m    = lane & 15;      // A row-in-tile / D col
    const int quad = lane >> 4;

    __shared__ __align__(16) float    xbuf[2048];
    __shared__ __align__(16) _Float16 vbuf[2][3][128];   // dbuf concat-h vectors
    __shared__ __align__(16) float    obuf[128];         // output ring (2 x 64)

    for (int i = tid; i < T; i += BLK) xbuf[i] = x[(size_t)b * T + i];
    for (int i = tid; i < 384; i += BLK) ((int*)vbuf)[i] = 0;   // zero both bufs

    auto fetchW = [&](int l, int s, int k) -> float {
        if (s >= 204) return (l == 2 && s == 204 && k >= 51 && k < 102) ? Wl[k - 51] : 0.f;
        const int r = (s & 3) * HID + (s >> 2);
        if (l == 0) {
            if (k < 51)  return Whh1[r * 51 + k];
            if (k <= 52) return Wih1[r];          // k=51 (x_hi) and k=52 (x_lo)
            return 0.f;
        }
        const size_t base = (size_t)(l - 1) * 204 * 51;
        if (k < 51)  return Wih[base + (size_t)r * 51 + k];
        if (k < 102) return Whh[base + (size_t)r * 51 + (k - 51)];
        return 0.f;
    };
    auto fetchB = [&](int l, int s) -> float {
        if (s >= 204) return (l == 2 && s == 204) ? bl[0] : 0.f;
        const int r = (s & 3) * HID + (s >> 2);
        if (l == 0) return bih1[r] + bhh1[r];
        return bih[(l - 1) * 204 + r] + bhh[(l - 1) * 204 + r];
    };

    // ---- A fragments (kernel lifetime): 10 = l0:{k0,k1} l1:{k0..3} l2:{k0..3}
    half8 afr[10];
    #pragma unroll
    for (int fi = 0; fi < 10; ++fi) {
        const int l  = (fi < 2) ? 0 : (fi < 6 ? 1 : 2);
        const int kt = (fi < 2) ? fi : (fi < 6 ? fi - 2 : fi - 6);
        #pragma unroll
        for (int j = 0; j < 8; ++j)
            afr[fi][j] = (_Float16)fetchW(l, 16 * wave + m, 32 * kt + quad * 8 + j);
    }
    // ---- bias folded into acc init: lane's D rows = 16w + quad*4 + reg
    f32x4 binit[3];
    #pragma unroll
    for (int l = 0; l < 3; ++l)
        #pragma unroll
        for (int r = 0; r < 4; ++r)
            binit[l][r] = fetchB(l, 16 * wave + quad * 4 + r);

    __syncthreads();
    if (tid == 0) {                                   // x(0) into buffer 0
        const float x0 = xbuf[0];
        const _Float16 xh = (_Float16)x0;
        vbuf[0][0][51] = xh;
        vbuf[0][0][52] = (_Float16)(x0 - (float)xh);
    }
    float c0 = 0.f, c1 = 0.f, c2 = 0.f;
    const int u = 4 * wave + quad;                    // unit owned by this lane
    __syncthreads();

    const int TICKS = T + 4;
    for (int tau = 0; tau < TICKS; ++tau) {
        const int par = tau & 1, nxt = par ^ 1;
        const _Float16* vb = &vbuf[par][0][0];
        const int qo = quad * 8;

        // ---- B fragments: column-replicated v (broadcast reads) ----
        const half8 b00 = *(const half8*)(vb + qo);
        const half8 b01 = *(const half8*)(vb + 32 + qo);
        half8 b1[4], b2[4];
        #pragma unroll
        for (int kt = 0; kt < 4; ++kt) {
            b1[kt] = *(const half8*)(vb + 128 + 32 * kt + qo);
            b2[kt] = *(const half8*)(vb + 256 + 32 * kt + qo);
        }

        // ---- gate pre-acts on the matrix pipe ----
        f32x4 g0 = binit[0], g1 = binit[1], g2 = binit[2];
        g0 = __builtin_amdgcn_mfma_f32_16x16x32_f16(afr[0], b00, g0, 0, 0, 0);
        g0 = __builtin_amdgcn_mfma_f32_16x16x32_f16(afr[1], b01, g0, 0, 0, 0);
        #pragma unroll
        for (int kt = 0; kt < 4; ++kt)
            g1 = __builtin_amdgcn_mfma_f32_16x16x32_f16(afr[2 + kt], b1[kt], g1, 0, 0, 0);
        #pragma unroll
        for (int kt = 0; kt < 4; ++kt)
            g2 = __builtin_amdgcn_mfma_f32_16x16x32_f16(afr[6 + kt], b2[kt], g2, 0, 0, 0);

        // ---- in-wave cell updates (g[0..3] = i,f,g,o of unit u) ----
        const bool wr = (m == 0) && (u < HID);
        if ((unsigned)tau < (unsigned)T) {
            c0 = fmaf(fsig(g0[1]), c0, fsig(g0[0]) * ftanh(g0[2]));
            const _Float16 h = (_Float16)(fsig(g0[3]) * ftanh(c0));
            if (wr) { vbuf[nxt][0][u] = h; vbuf[nxt][1][u] = h; }
        }
        if ((unsigned)(tau - 1) < (unsigned)T) {
            c1 = fmaf(fsig(g1[1]), c1, fsig(g1[0]) * ftanh(g1[2]));
            const _Float16 h = (_Float16)(fsig(g1[3]) * ftanh(c1));
            if (wr) { vbuf[nxt][1][HID + u] = h; vbuf[nxt][2][u] = h; }
        }
        if ((unsigned)(tau - 2) < (unsigned)T) {
            c2 = fmaf(fsig(g2[1]), c2, fsig(g2[0]) * ftanh(g2[2]));
            const _Float16 h = (_Float16)(fsig(g2[3]) * ftanh(c2));
            if (wr) vbuf[nxt][2][HID + u] = h;
        }
        // output row 204 = D row (quad=3, reg=0) of wave 12
        if (wave == 12 && lane == 48 && (unsigned)(tau - 3) < (unsigned)T)
            obuf[(tau - 3) & 127] = g2[0];
        // x(tau+1) into the next buffer (f16 hi+lo split, ~exact)
        if (wave == 0 && lane == 1) {
            const int tn = tau + 1;
            const float xv = xbuf[tn < T ? tn : 0];
            const _Float16 xh = (_Float16)xv;
            vbuf[nxt][0][51] = xh;
            vbuf[nxt][0][52] = (_Float16)(xv - (float)xh);
        }
        // coalesced flush: slots read were all written before the last barrier
        if (wave == 1 && (tau & 63) == 3 && tau >= 67) {
            const int t0 = tau - 67;                  // multiple of 64
            out[(size_t)b * T + t0 + lane] = obuf[(t0 & 64) + lane];
        }
        __syncthreads();
    }
}

extern "C" void kernel_launch(void* const* d_in, const int* in_sizes, int n_in,
                              void* d_out, int out_size, void* d_ws, size_t ws_size,
                              hipStream_t stream) {
    const float* x    = (const float*)d_in[0];
    const float* Wih1 = (const float*)d_in[1];
    const float* Whh1 = (const float*)d_in[2];
    const float* bih1 = (const float*)d_in[3];
    const float* bhh1 = (const float*)d_in[4];
    const float* Wih  = (const float*)d_in[5];
    const float* Whh  = (const float*)d_in[6];
    const float* bih  = (const float*)d_in[7];
    const float* bhh  = (const float*)d_in[8];
    const float* Wl   = (const float*)d_in[9];
    const float* bl   = (const float*)d_in[10];
    float* out = (float*)d_out;

    const int T = in_sizes[0] / BATCH;   // 2048 (flush assumes T % 64 == 0)
    lstm3_kernel<<<BATCH, BLK, 0, stream>>>(x, Wih1, Whh1, bih1, bhh1,
                                            Wih, Whh, bih, bhh, Wl, bl, out, T);
}